// Round 9
// baseline (204.344 us; speedup 1.0000x reference)
//
#include <hip/hip_runtime.h>
#include <stdint.h>

// VQ codebook argmin. N=2048 queries (C=64) vs K=81920 codes.
// out (f32): [quantized_st 131072][vq_loss][commit_loss][idx 2048]
//
// Structure: bf16 convert(+zero init) -> MFMA pass1 (block max over 5 slices,
// atomic/barrier-minimal) -> qmax reduce -> MFMA collect (same 5-slice loop,
// candidates via DMARG threshold) -> fused exact rescore+finalize -> losses.
// Margin: numpy winner satisfies dot_bf(k*) >= max_bf - (3.9e-6 + 2*eps),
// eps <= 2^-8*||z||*||e|| <= 4.2e-6 => bound 1.23e-5; DMARG=1.6e-5.
// CAP=64 + exact full-scan fallback on overflow.
#define NQ 2048
#define KK 81920
#define CD 64
#define CAP 64
#define DMARG 1.6e-5f
#define QPB 128              // queries per q-block (8 groups of 16)
#define NSLICE 160           // code slices of 512
#define SPX 20               // slices per XCD
#define SPB 5                // slices per block
#define NQBLK 16

#define OUT_VQ 131072
#define OUT_CM 131073
#define OUT_IDX 131074

// ws layout (bytes)
#define WS_QMAX 0            // u32[2048]  f2o(max bf16 dot)
#define WS_CNT  8192         // int[2048]  candidate counts (zeroed by convert)
#define WS_KEYS 16384        // u64[2048]
#define WS_LOSS 32768        // float
#define WS_CAND 33024        // int[2048*CAP]  (524288 B)
#define WS_ZBF  589824       // ushort[131072]   bf16 z      (262144 B)
#define WS_EBF  851968       // ushort[5242880]  bf16 emb    (10485760 B)
#define WS_BMAX 11337728     // u32[2048*32] per-(q, xcd*4+sgrp) max (262144 B)

typedef short v8s __attribute__((ext_vector_type(8)));
typedef float v4f __attribute__((ext_vector_type(4)));

__device__ __forceinline__ unsigned int f2o(float f) {
  unsigned int u = __float_as_uint(f);
  return (u & 0x80000000u) ? ~u : (u | 0x80000000u);
}
__device__ __forceinline__ float o2f(unsigned int u) {
  unsigned int v = (u & 0x80000000u) ? (u & 0x7FFFFFFFu) : ~u;
  return __uint_as_float(v);
}
__device__ __forceinline__ unsigned int bf16rne(float f) {
  unsigned int u = __float_as_uint(f);
  u = u + 0x7FFFu + ((u >> 16) & 1u);
  return u >> 16;
}

// fp32 -> bf16 for z then emb (grid-stride); also zeroes cnt/loss.
#define NZ4 32768
#define NTOT4 1343488
__global__ __launch_bounds__(256) void convert_kernel(
    const float* __restrict__ z, const float* __restrict__ emb,
    unsigned int* __restrict__ zbf, unsigned int* __restrict__ ebf,
    int* __restrict__ cnt, float* __restrict__ loss) {
  const int gid = blockIdx.x * 256 + threadIdx.x;
  if (gid < NQ) cnt[gid] = 0;
  if (gid == NQ) *loss = 0.0f;
  const int stride = gridDim.x * 256;
#pragma unroll 1
  for (int i = gid; i < NTOT4; i += stride) {
    const bool isz = (i < NZ4);
    const float4 v = isz ? ((const float4*)z)[i] : ((const float4*)emb)[i - NZ4];
    uint2 o;
    o.x = bf16rne(v.x) | (bf16rne(v.y) << 16);
    o.y = bf16rne(v.z) | (bf16rne(v.w) << 16);
    if (isz) ((uint2*)zbf)[i] = o;
    else     ((uint2*)ebf)[i - NZ4] = o;
  }
}

// Block decode. xcd = bid&7 (round-robin dispatch); within an XCD, qblk
// varies fastest (L2 B-slice reuse, different output queries). Each block
// owns 5 consecutive slices (sgrp) and 128 queries.
struct BlkMap { int q0, slice0, xcd, sgrp; };
__device__ __forceinline__ BlkMap decode_block(int bid) {
  BlkMap m;
  m.xcd = bid & 7;
  const int i = bid >> 3;          // 0..63
  const int qblk = i & 15;         // fastest
  m.sgrp = i >> 4;                 // 0..3
  m.q0 = qblk * QPB;
  m.slice0 = m.xcd * SPX + m.sgrp * SPB;
  return m;
}

__device__ __forceinline__ void load_B(v8s (&Bb)[8][2],
                                       const unsigned short* __restrict__ ebf,
                                       int code0, int lrow, int quad) {
#pragma unroll
  for (int cg = 0; cg < 8; ++cg) {
    const unsigned short* er = ebf + (size_t)(code0 + cg * 16 + lrow) * CD + quad * 8;
    Bb[cg][0] = *(const v8s*)er;
    Bb[cg][1] = *(const v8s*)(er + 32);
  }
}

// mfma_f32_16x16x32_bf16 layouts (m89/m91/m120):
//   A: lane holds A[m=lane&15][k=quad*8+j]; B: B[k=quad*8+j][n=lane&15]
//   D: lane,reg r -> D[row=quad*4+r][col=lane&15] (row=query, col=code)
// Wave w owns codes [slice*512 + w*128, +128). B double-buffered in regs:
// next slice's 16 loads issue while current slice's 128 MFMAs run.
__global__ __launch_bounds__(256, 2) void pass1_kernel(
    const unsigned short* __restrict__ zbf, const unsigned short* __restrict__ ebf,
    unsigned int* __restrict__ bmax) {
  const int tid = threadIdx.x;
  const int wave = tid >> 6, lane = tid & 63;
  const int quad = lane >> 4, lrow = lane & 15;
  const BlkMap bm = decode_block(blockIdx.x);

  v8s A0[8], A1[8];
#pragma unroll
  for (int qg = 0; qg < 8; ++qg) {
    const unsigned short* zr = zbf + (size_t)(bm.q0 + qg * 16 + lrow) * CD + quad * 8;
    A0[qg] = *(const v8s*)zr;
    A1[qg] = *(const v8s*)(zr + 32);
  }

  float pmax[8][4];
#pragma unroll
  for (int qg = 0; qg < 8; ++qg)
#pragma unroll
    for (int r = 0; r < 4; ++r) pmax[qg][r] = -1e30f;

  v8s B[2][8][2];
  load_B(B[0], ebf, bm.slice0 * 512 + wave * 128, lrow, quad);
#pragma unroll
  for (int s = 0; s < SPB; ++s) {
    const int cur = s & 1;
    if (s + 1 < SPB)
      load_B(B[cur ^ 1], ebf, (bm.slice0 + s + 1) * 512 + wave * 128, lrow, quad);
#pragma unroll
    for (int qg = 0; qg < 8; ++qg) {
#pragma unroll
      for (int cg = 0; cg < 8; ++cg) {
        v4f acc = {0.f, 0.f, 0.f, 0.f};
        acc = __builtin_amdgcn_mfma_f32_16x16x32_bf16(A0[qg], B[cur][cg][0], acc, 0, 0, 0);
        acc = __builtin_amdgcn_mfma_f32_16x16x32_bf16(A1[qg], B[cur][cg][1], acc, 0, 0, 0);
#pragma unroll
        for (int r = 0; r < 4; ++r) pmax[qg][r] = fmaxf(pmax[qg][r], acc[r]);
      }
    }
  }

  // batched 16-lane max reduce (32 independent chains per level)
#pragma unroll
  for (int m = 1; m <= 8; m <<= 1)
#pragma unroll
    for (int qg = 0; qg < 8; ++qg)
#pragma unroll
      for (int r = 0; r < 4; ++r)
        pmax[qg][r] = fmaxf(pmax[qg][r], __shfl_xor(pmax[qg][r], m, 64));

  __shared__ unsigned int smax[4][QPB];
  if (lrow == 0) {
#pragma unroll
    for (int qg = 0; qg < 8; ++qg) {
      uint4 v;
      v.x = f2o(pmax[qg][0]); v.y = f2o(pmax[qg][1]);
      v.z = f2o(pmax[qg][2]); v.w = f2o(pmax[qg][3]);
      *(uint4*)&smax[wave][qg * 16 + quad * 4] = v;
    }
  }
  __syncthreads();
  if (tid < QPB) {
    unsigned int m0 = smax[0][tid], m1 = smax[1][tid];
    unsigned int m2 = smax[2][tid], m3 = smax[3][tid];
    unsigned int m01 = m0 > m1 ? m0 : m1;
    unsigned int m23 = m2 > m3 ? m2 : m3;
    bmax[(size_t)(bm.q0 + tid) * 32 + bm.xcd * 4 + bm.sgrp] = m01 > m23 ? m01 : m23;
  }
}

// qmax[q] = max over 32 block maxima. 8 queries per block (32 lanes each).
__global__ __launch_bounds__(256) void reduce_qmax_kernel(
    const unsigned int* __restrict__ bmax, unsigned int* __restrict__ qmax) {
  const int t = threadIdx.x;
  const int q = blockIdx.x * 8 + (t >> 5);
  const int j = t & 31;
  unsigned int m = bmax[(size_t)q * 32 + j];
#pragma unroll
  for (int s = 16; s; s >>= 1) {
    unsigned int o = (unsigned int)__shfl_xor((int)m, s, 64);
    m = m > o ? m : o;
  }
  if (j == 0) qmax[q] = m;
}

// Collect: bit-identical MFMA chains; k with dot >= qmax - DMARG.
__global__ __launch_bounds__(256, 2) void collect_kernel(
    const unsigned short* __restrict__ zbf, const unsigned short* __restrict__ ebf,
    const unsigned int* __restrict__ qmax, int* __restrict__ cnt,
    int* __restrict__ cand) {
  const int tid = threadIdx.x;
  const int wave = tid >> 6, lane = tid & 63;
  const int quad = lane >> 4, lrow = lane & 15;
  const BlkMap bm = decode_block(blockIdx.x);

  v8s A0[8], A1[8];
#pragma unroll
  for (int qg = 0; qg < 8; ++qg) {
    const unsigned short* zr = zbf + (size_t)(bm.q0 + qg * 16 + lrow) * CD + quad * 8;
    A0[qg] = *(const v8s*)zr;
    A1[qg] = *(const v8s*)(zr + 32);
  }
  float thr[8][4];
#pragma unroll
  for (int qg = 0; qg < 8; ++qg) {
    const uint4 tv = *(const uint4*)(qmax + bm.q0 + qg * 16 + quad * 4);
    thr[qg][0] = o2f(tv.x) - DMARG; thr[qg][1] = o2f(tv.y) - DMARG;
    thr[qg][2] = o2f(tv.z) - DMARG; thr[qg][3] = o2f(tv.w) - DMARG;
  }

  v8s B[2][8][2];
  load_B(B[0], ebf, bm.slice0 * 512 + wave * 128, lrow, quad);
#pragma unroll
  for (int s = 0; s < SPB; ++s) {
    const int cur = s & 1;
    if (s + 1 < SPB)
      load_B(B[cur ^ 1], ebf, (bm.slice0 + s + 1) * 512 + wave * 128, lrow, quad);
    const int scode0 = (bm.slice0 + s) * 512 + wave * 128;
#pragma unroll
    for (int qg = 0; qg < 8; ++qg) {
#pragma unroll
      for (int cg = 0; cg < 8; ++cg) {
        v4f acc = {0.f, 0.f, 0.f, 0.f};
        acc = __builtin_amdgcn_mfma_f32_16x16x32_bf16(A0[qg], B[cur][cg][0], acc, 0, 0, 0);
        acc = __builtin_amdgcn_mfma_f32_16x16x32_bf16(A1[qg], B[cur][cg][1], acc, 0, 0, 0);
        const float m01 = fmaxf(acc[0] - thr[qg][0], acc[1] - thr[qg][1]);
        const float m23 = fmaxf(acc[2] - thr[qg][2], acc[3] - thr[qg][3]);
        if (fmaxf(m01, m23) >= 0.0f) {  // rare (~6 hits/query total)
          const int code = scode0 + cg * 16 + lrow;
#pragma unroll
          for (int r = 0; r < 4; ++r) {
            if (acc[r] >= thr[qg][r]) {
              const int q = bm.q0 + qg * 16 + quad * 4 + r;
              const int pos = atomicAdd(&cnt[q], 1);
              if (pos < CAP) cand[q * CAP + pos] = code;
            }
          }
        }
      }
    }
  }
}

// Exact bitwise-numpy score of code k (round-2/3 verified DAG).
__device__ __forceinline__ unsigned long long exact_key(
    const float* __restrict__ emb, const float zr[CD], float zn2, int k) {
#pragma clang fp contract(off)
  float er[CD];
  const float4* ep = (const float4*)(emb + (size_t)k * CD);
#pragma unroll
  for (int j = 0; j < 16; ++j) {
    float4 v = ep[j];
    er[4 * j] = v.x; er[4 * j + 1] = v.y; er[4 * j + 2] = v.z; er[4 * j + 3] = v.w;
  }
  float acc[16];
#pragma unroll
  for (int j = 0; j < 16; ++j) acc[j] = 0.0f;
#pragma unroll
  for (int q4 = 0; q4 < 16; ++q4) {
    const int jb = 4 * (q4 & 3), cb = 4 * q4;
    acc[jb + 0] = __builtin_fmaf(er[cb + 0], zr[cb + 0], acc[jb + 0]);
    acc[jb + 1] = __builtin_fmaf(er[cb + 1], zr[cb + 1], acc[jb + 1]);
    acc[jb + 2] = __builtin_fmaf(er[cb + 2], zr[cb + 2], acc[jb + 2]);
    acc[jb + 3] = __builtin_fmaf(er[cb + 3], zr[cb + 3], acc[jb + 3]);
  }
  float b8[8], b4[4];
#pragma unroll
  for (int j = 0; j < 8; ++j) b8[j] = acc[j] + acc[j + 8];
#pragma unroll
  for (int j = 0; j < 4; ++j) b4[j] = b8[j] + b8[j + 4];
  const float dot = (b4[0] + b4[2]) + (b4[1] + b4[3]);
  const float t = zn2 - 2.0f * dot;  // single rounding == numpy A - 2B
  return ((unsigned long long)f2o(t) << 32) | (unsigned int)k;
}

// Fused rescore+finalize. One WAVE per query: lane l rescores candidate
// slot l (full-scan fallback on overflow); u64 shuffle-min; then the same
// wave writes quantized_st (lane=channel), idx, and loss partial.
__global__ __launch_bounds__(256) void rescore_finalize_kernel(
    const float* __restrict__ z, const float* __restrict__ emb,
    const int* __restrict__ cnt, const int* __restrict__ cand,
    unsigned long long* __restrict__ keys, float* __restrict__ out,
    float* __restrict__ loss) {
#pragma clang fp contract(off)
  const int t = threadIdx.x;
  const int wv = t >> 6, lane = t & 63;
  const int n = blockIdx.x * 4 + wv;

  float zr[CD];
  {
    const float4* zp = (const float4*)(z + (size_t)n * CD);
#pragma unroll
    for (int i = 0; i < 16; ++i) {
      float4 v = zp[i];
      zr[4 * i] = v.x; zr[4 * i + 1] = v.y; zr[4 * i + 2] = v.z; zr[4 * i + 3] = v.w;
    }
  }
  float zn2;
  {
    float r[8];
#pragma unroll
    for (int j = 0; j < 8; ++j) r[j] = zr[j] * zr[j];
#pragma unroll
    for (int i = 8; i < CD; i += 8)
#pragma unroll
      for (int j = 0; j < 8; ++j) r[j] += zr[i + j] * zr[i + j];
    zn2 = ((r[0] + r[1]) + (r[2] + r[3])) + ((r[4] + r[5]) + (r[6] + r[7]));
  }

  const int c = cnt[n];
  unsigned long long best = ~0ull;
  if (c <= CAP) {
    if (lane < c) best = exact_key(emb, zr, zn2, cand[n * CAP + lane]);
  } else {
#pragma unroll 1
    for (int k = lane; k < KK; k += 64) {
      unsigned long long key = exact_key(emb, zr, zn2, k);
      best = (key < best) ? key : best;
    }
  }
#pragma unroll
  for (int m = 32; m; m >>= 1) {
    unsigned long long o = __shfl_xor(best, m, 64);
    best = (o < best) ? o : best;
  }
  const int idx = (int)(best & 0xFFFFFFFFull);
  if (lane == 0) keys[n] = best;

  // finalize: lane = channel. quantized_st = z + (q - z), two f32 roundings.
  const float e = emb[(size_t)idx * CD + lane];
  const float zv = z[(size_t)n * CD + lane];
  const float dst = e - zv;
  out[(size_t)n * CD + lane] = zv + dst;
  if (lane == 0) out[OUT_IDX + n] = (float)idx;
  float d = zv - e;
  float sq = d * d;
#pragma unroll
  for (int off = 32; off > 0; off >>= 1) sq += __shfl_down(sq, off, 64);
  __shared__ float part[4];
  if (lane == 0) part[wv] = sq;
  __syncthreads();
  if (t == 0) atomicAdd(loss, part[0] + part[1] + part[2] + part[3]);
}

__global__ void write_losses(const float* __restrict__ loss, float* __restrict__ out) {
  float m = *loss / (float)(NQ * CD);
  out[OUT_VQ] = m;
  out[OUT_CM] = m;
}

extern "C" void kernel_launch(void* const* d_in, const int* in_sizes, int n_in,
                              void* d_out, int out_size, void* d_ws, size_t ws_size,
                              hipStream_t stream) {
  const float* z = (const float*)d_in[0];
  const float* emb = (const float*)d_in[1];
  float* out = (float*)d_out;
  char* ws = (char*)d_ws;
  unsigned int* qmax = (unsigned int*)(ws + WS_QMAX);
  int* cnt = (int*)(ws + WS_CNT);
  unsigned long long* keys = (unsigned long long*)(ws + WS_KEYS);
  float* loss = (float*)(ws + WS_LOSS);
  int* cand = (int*)(ws + WS_CAND);
  unsigned int* zbf = (unsigned int*)(ws + WS_ZBF);
  unsigned int* ebf = (unsigned int*)(ws + WS_EBF);
  unsigned int* bmax = (unsigned int*)(ws + WS_BMAX);

  convert_kernel<<<1312, 256, 0, stream>>>(z, emb, zbf, ebf, cnt, loss);
  pass1_kernel<<<512, 256, 0, stream>>>(
      (const unsigned short*)zbf, (const unsigned short*)ebf, bmax);
  reduce_qmax_kernel<<<NQ / 8, 256, 0, stream>>>(bmax, qmax);
  collect_kernel<<<512, 256, 0, stream>>>(
      (const unsigned short*)zbf, (const unsigned short*)ebf, qmax, cnt, cand);
  rescore_finalize_kernel<<<NQ / 4, 256, 0, stream>>>(z, emb, cnt, cand, keys, out, loss);
  write_losses<<<1, 1, 0, stream>>>(loss, out);
}

// Round 10
// 152.134 us; speedup vs baseline: 1.3432x; 1.3432x over previous
//
#include <hip/hip_runtime.h>
#include <stdint.h>

// VQ codebook argmin. N=2048 queries (C=64) vs K=81920 codes.
// out (f32): [quantized_st 131072][vq_loss][commit_loss][idx 2048]
//
// Structure: bf16 convert(+zero init) -> MFMA pass1 (block max over 5 slices)
// -> qmax reduce -> MFMA collect (same loop, DMARG threshold) -> fused exact
// rescore+finalize -> losses.
// Margin: numpy winner satisfies dot_bf(k*) >= max_bf - (3.9e-6 + 2*eps),
// eps <= 2^-8*||z||*||e|| <= 4.2e-6 => bound 1.23e-5; DMARG=1.6e-5.
// CAP=64 + exact full-scan fallback on overflow.
//
// R10: SPILL FIX. r9's B double-buffer pushed the budget to ~280 VGPR > the
// 256 cap from __launch_bounds__(256,2) -> 103 MB/pass scratch writes (the
// WRITE_SIZE smoking gun). Single-buffered B keeps A(64)+B(64)+pmax/thr(32)
// +temps ~= 190 VGPR -> no scratch, 2 waves/SIMD.
#define NQ 2048
#define KK 81920
#define CD 64
#define CAP 64
#define DMARG 1.6e-5f
#define QPB 128              // queries per q-block (8 groups of 16)
#define NSLICE 160           // code slices of 512
#define SPX 20               // slices per XCD
#define SPB 5                // slices per block
#define NQBLK 16

#define OUT_VQ 131072
#define OUT_CM 131073
#define OUT_IDX 131074

// ws layout (bytes)
#define WS_QMAX 0            // u32[2048]  f2o(max bf16 dot)
#define WS_CNT  8192         // int[2048]  candidate counts (zeroed by convert)
#define WS_KEYS 16384        // u64[2048]
#define WS_LOSS 32768        // float
#define WS_CAND 33024        // int[2048*CAP]  (524288 B)
#define WS_ZBF  589824       // ushort[131072]   bf16 z      (262144 B)
#define WS_EBF  851968       // ushort[5242880]  bf16 emb    (10485760 B)
#define WS_BMAX 11337728     // u32[2048*32] per-(q, xcd*4+sgrp) max (262144 B)

typedef short v8s __attribute__((ext_vector_type(8)));
typedef float v4f __attribute__((ext_vector_type(4)));

__device__ __forceinline__ unsigned int f2o(float f) {
  unsigned int u = __float_as_uint(f);
  return (u & 0x80000000u) ? ~u : (u | 0x80000000u);
}
__device__ __forceinline__ float o2f(unsigned int u) {
  unsigned int v = (u & 0x80000000u) ? (u & 0x7FFFFFFFu) : ~u;
  return __uint_as_float(v);
}
__device__ __forceinline__ unsigned int bf16rne(float f) {
  unsigned int u = __float_as_uint(f);
  u = u + 0x7FFFu + ((u >> 16) & 1u);
  return u >> 16;
}

// fp32 -> bf16 for z then emb (grid-stride); also zeroes cnt/loss.
#define NZ4 32768
#define NTOT4 1343488
__global__ __launch_bounds__(256) void convert_kernel(
    const float* __restrict__ z, const float* __restrict__ emb,
    unsigned int* __restrict__ zbf, unsigned int* __restrict__ ebf,
    int* __restrict__ cnt, float* __restrict__ loss) {
  const int gid = blockIdx.x * 256 + threadIdx.x;
  if (gid < NQ) cnt[gid] = 0;
  if (gid == NQ) *loss = 0.0f;
  const int stride = gridDim.x * 256;
#pragma unroll 1
  for (int i = gid; i < NTOT4; i += stride) {
    const bool isz = (i < NZ4);
    const float4 v = isz ? ((const float4*)z)[i] : ((const float4*)emb)[i - NZ4];
    uint2 o;
    o.x = bf16rne(v.x) | (bf16rne(v.y) << 16);
    o.y = bf16rne(v.z) | (bf16rne(v.w) << 16);
    if (isz) ((uint2*)zbf)[i] = o;
    else     ((uint2*)ebf)[i - NZ4] = o;
  }
}

// Block decode. xcd = bid&7 (round-robin dispatch); within an XCD, qblk
// varies fastest (L2 B-slice reuse, different output queries). Each block
// owns 5 consecutive slices (sgrp) and 128 queries.
struct BlkMap { int q0, slice0, xcd, sgrp; };
__device__ __forceinline__ BlkMap decode_block(int bid) {
  BlkMap m;
  m.xcd = bid & 7;
  const int i = bid >> 3;          // 0..63
  const int qblk = i & 15;         // fastest
  m.sgrp = i >> 4;                 // 0..3
  m.q0 = qblk * QPB;
  m.slice0 = m.xcd * SPX + m.sgrp * SPB;
  return m;
}

__device__ __forceinline__ void load_B(v8s (&Bb)[8][2],
                                       const unsigned short* __restrict__ ebf,
                                       int code0, int lrow, int quad) {
#pragma unroll
  for (int cg = 0; cg < 8; ++cg) {
    const unsigned short* er = ebf + (size_t)(code0 + cg * 16 + lrow) * CD + quad * 8;
    Bb[cg][0] = *(const v8s*)er;
    Bb[cg][1] = *(const v8s*)(er + 32);
  }
}

// mfma_f32_16x16x32_bf16 layouts (m89/m91/m120):
//   A: lane holds A[m=lane&15][k=quad*8+j]; B: B[k=quad*8+j][n=lane&15]
//   D: lane,reg r -> D[row=quad*4+r][col=lane&15] (row=query, col=code)
// Wave w owns codes [slice*512 + w*128, +128). Single-buffered B (spill-free).
__global__ __launch_bounds__(256, 2) void pass1_kernel(
    const unsigned short* __restrict__ zbf, const unsigned short* __restrict__ ebf,
    unsigned int* __restrict__ bmax) {
  const int tid = threadIdx.x;
  const int wave = tid >> 6, lane = tid & 63;
  const int quad = lane >> 4, lrow = lane & 15;
  const BlkMap bm = decode_block(blockIdx.x);

  v8s A0[8], A1[8];
#pragma unroll
  for (int qg = 0; qg < 8; ++qg) {
    const unsigned short* zr = zbf + (size_t)(bm.q0 + qg * 16 + lrow) * CD + quad * 8;
    A0[qg] = *(const v8s*)zr;
    A1[qg] = *(const v8s*)(zr + 32);
  }

  float pmax[8][4];
#pragma unroll
  for (int qg = 0; qg < 8; ++qg)
#pragma unroll
    for (int r = 0; r < 4; ++r) pmax[qg][r] = -1e30f;

#pragma unroll 1
  for (int s = 0; s < SPB; ++s) {
    v8s B[8][2];
    load_B(B, ebf, (bm.slice0 + s) * 512 + wave * 128, lrow, quad);
#pragma unroll
    for (int qg = 0; qg < 8; ++qg) {
#pragma unroll
      for (int cg = 0; cg < 8; ++cg) {
        v4f acc = {0.f, 0.f, 0.f, 0.f};
        acc = __builtin_amdgcn_mfma_f32_16x16x32_bf16(A0[qg], B[cg][0], acc, 0, 0, 0);
        acc = __builtin_amdgcn_mfma_f32_16x16x32_bf16(A1[qg], B[cg][1], acc, 0, 0, 0);
#pragma unroll
        for (int r = 0; r < 4; ++r) pmax[qg][r] = fmaxf(pmax[qg][r], acc[r]);
      }
    }
  }

  // batched 16-lane max reduce (32 independent chains per level)
#pragma unroll
  for (int m = 1; m <= 8; m <<= 1)
#pragma unroll
    for (int qg = 0; qg < 8; ++qg)
#pragma unroll
      for (int r = 0; r < 4; ++r)
        pmax[qg][r] = fmaxf(pmax[qg][r], __shfl_xor(pmax[qg][r], m, 64));

  __shared__ unsigned int smax[4][QPB];
  if (lrow == 0) {
#pragma unroll
    for (int qg = 0; qg < 8; ++qg) {
      uint4 v;
      v.x = f2o(pmax[qg][0]); v.y = f2o(pmax[qg][1]);
      v.z = f2o(pmax[qg][2]); v.w = f2o(pmax[qg][3]);
      *(uint4*)&smax[wave][qg * 16 + quad * 4] = v;
    }
  }
  __syncthreads();
  if (tid < QPB) {
    unsigned int m0 = smax[0][tid], m1 = smax[1][tid];
    unsigned int m2 = smax[2][tid], m3 = smax[3][tid];
    unsigned int m01 = m0 > m1 ? m0 : m1;
    unsigned int m23 = m2 > m3 ? m2 : m3;
    bmax[(size_t)(bm.q0 + tid) * 32 + bm.xcd * 4 + bm.sgrp] = m01 > m23 ? m01 : m23;
  }
}

// qmax[q] = max over 32 block maxima. 8 queries per block (32 lanes each).
__global__ __launch_bounds__(256) void reduce_qmax_kernel(
    const unsigned int* __restrict__ bmax, unsigned int* __restrict__ qmax) {
  const int t = threadIdx.x;
  const int q = blockIdx.x * 8 + (t >> 5);
  const int j = t & 31;
  unsigned int m = bmax[(size_t)q * 32 + j];
#pragma unroll
  for (int s = 16; s; s >>= 1) {
    unsigned int o = (unsigned int)__shfl_xor((int)m, s, 64);
    m = m > o ? m : o;
  }
  if (j == 0) qmax[q] = m;
}

// Collect: bit-identical MFMA chains; k with dot >= qmax - DMARG.
__global__ __launch_bounds__(256, 2) void collect_kernel(
    const unsigned short* __restrict__ zbf, const unsigned short* __restrict__ ebf,
    const unsigned int* __restrict__ qmax, int* __restrict__ cnt,
    int* __restrict__ cand) {
  const int tid = threadIdx.x;
  const int wave = tid >> 6, lane = tid & 63;
  const int quad = lane >> 4, lrow = lane & 15;
  const BlkMap bm = decode_block(blockIdx.x);

  v8s A0[8], A1[8];
#pragma unroll
  for (int qg = 0; qg < 8; ++qg) {
    const unsigned short* zr = zbf + (size_t)(bm.q0 + qg * 16 + lrow) * CD + quad * 8;
    A0[qg] = *(const v8s*)zr;
    A1[qg] = *(const v8s*)(zr + 32);
  }
  float thr[8][4];
#pragma unroll
  for (int qg = 0; qg < 8; ++qg) {
    const uint4 tv = *(const uint4*)(qmax + bm.q0 + qg * 16 + quad * 4);
    thr[qg][0] = o2f(tv.x) - DMARG; thr[qg][1] = o2f(tv.y) - DMARG;
    thr[qg][2] = o2f(tv.z) - DMARG; thr[qg][3] = o2f(tv.w) - DMARG;
  }

#pragma unroll 1
  for (int s = 0; s < SPB; ++s) {
    v8s B[8][2];
    const int scode0 = (bm.slice0 + s) * 512 + wave * 128;
    load_B(B, ebf, scode0, lrow, quad);
#pragma unroll
    for (int qg = 0; qg < 8; ++qg) {
#pragma unroll
      for (int cg = 0; cg < 8; ++cg) {
        v4f acc = {0.f, 0.f, 0.f, 0.f};
        acc = __builtin_amdgcn_mfma_f32_16x16x32_bf16(A0[qg], B[cg][0], acc, 0, 0, 0);
        acc = __builtin_amdgcn_mfma_f32_16x16x32_bf16(A1[qg], B[cg][1], acc, 0, 0, 0);
        const float m01 = fmaxf(acc[0] - thr[qg][0], acc[1] - thr[qg][1]);
        const float m23 = fmaxf(acc[2] - thr[qg][2], acc[3] - thr[qg][3]);
        if (fmaxf(m01, m23) >= 0.0f) {  // rare (~6 hits/query total)
          const int code = scode0 + cg * 16 + lrow;
#pragma unroll
          for (int r = 0; r < 4; ++r) {
            if (acc[r] >= thr[qg][r]) {
              const int q = bm.q0 + qg * 16 + quad * 4 + r;
              const int pos = atomicAdd(&cnt[q], 1);
              if (pos < CAP) cand[q * CAP + pos] = code;
            }
          }
        }
      }
    }
  }
}

// Exact bitwise-numpy score of code k (round-2/3 verified DAG).
__device__ __forceinline__ unsigned long long exact_key(
    const float* __restrict__ emb, const float zr[CD], float zn2, int k) {
#pragma clang fp contract(off)
  float er[CD];
  const float4* ep = (const float4*)(emb + (size_t)k * CD);
#pragma unroll
  for (int j = 0; j < 16; ++j) {
    float4 v = ep[j];
    er[4 * j] = v.x; er[4 * j + 1] = v.y; er[4 * j + 2] = v.z; er[4 * j + 3] = v.w;
  }
  float acc[16];
#pragma unroll
  for (int j = 0; j < 16; ++j) acc[j] = 0.0f;
#pragma unroll
  for (int q4 = 0; q4 < 16; ++q4) {
    const int jb = 4 * (q4 & 3), cb = 4 * q4;
    acc[jb + 0] = __builtin_fmaf(er[cb + 0], zr[cb + 0], acc[jb + 0]);
    acc[jb + 1] = __builtin_fmaf(er[cb + 1], zr[cb + 1], acc[jb + 1]);
    acc[jb + 2] = __builtin_fmaf(er[cb + 2], zr[cb + 2], acc[jb + 2]);
    acc[jb + 3] = __builtin_fmaf(er[cb + 3], zr[cb + 3], acc[jb + 3]);
  }
  float b8[8], b4[4];
#pragma unroll
  for (int j = 0; j < 8; ++j) b8[j] = acc[j] + acc[j + 8];
#pragma unroll
  for (int j = 0; j < 4; ++j) b4[j] = b8[j] + b8[j + 4];
  const float dot = (b4[0] + b4[2]) + (b4[1] + b4[3]);
  const float t = zn2 - 2.0f * dot;  // single rounding == numpy A - 2B
  return ((unsigned long long)f2o(t) << 32) | (unsigned int)k;
}

// Fused rescore+finalize. One WAVE per query: lane l rescores candidate
// slot l (full-scan fallback on overflow); u64 shuffle-min; then the same
// wave writes quantized_st (lane=channel), idx, and loss partial.
__global__ __launch_bounds__(256) void rescore_finalize_kernel(
    const float* __restrict__ z, const float* __restrict__ emb,
    const int* __restrict__ cnt, const int* __restrict__ cand,
    unsigned long long* __restrict__ keys, float* __restrict__ out,
    float* __restrict__ loss) {
#pragma clang fp contract(off)
  const int t = threadIdx.x;
  const int wv = t >> 6, lane = t & 63;
  const int n = blockIdx.x * 4 + wv;

  float zr[CD];
  {
    const float4* zp = (const float4*)(z + (size_t)n * CD);
#pragma unroll
    for (int i = 0; i < 16; ++i) {
      float4 v = zp[i];
      zr[4 * i] = v.x; zr[4 * i + 1] = v.y; zr[4 * i + 2] = v.z; zr[4 * i + 3] = v.w;
    }
  }
  float zn2;
  {
    float r[8];
#pragma unroll
    for (int j = 0; j < 8; ++j) r[j] = zr[j] * zr[j];
#pragma unroll
    for (int i = 8; i < CD; i += 8)
#pragma unroll
      for (int j = 0; j < 8; ++j) r[j] += zr[i + j] * zr[i + j];
    zn2 = ((r[0] + r[1]) + (r[2] + r[3])) + ((r[4] + r[5]) + (r[6] + r[7]));
  }

  const int c = cnt[n];
  unsigned long long best = ~0ull;
  if (c <= CAP) {
    if (lane < c) best = exact_key(emb, zr, zn2, cand[n * CAP + lane]);
  } else {
#pragma unroll 1
    for (int k = lane; k < KK; k += 64) {
      unsigned long long key = exact_key(emb, zr, zn2, k);
      best = (key < best) ? key : best;
    }
  }
#pragma unroll
  for (int m = 32; m; m >>= 1) {
    unsigned long long o = __shfl_xor(best, m, 64);
    best = (o < best) ? o : best;
  }
  const int idx = (int)(best & 0xFFFFFFFFull);
  if (lane == 0) keys[n] = best;

  // finalize: lane = channel. quantized_st = z + (q - z), two f32 roundings.
  const float e = emb[(size_t)idx * CD + lane];
  const float zv = z[(size_t)n * CD + lane];
  const float dst = e - zv;
  out[(size_t)n * CD + lane] = zv + dst;
  if (lane == 0) out[OUT_IDX + n] = (float)idx;
  float d = zv - e;
  float sq = d * d;
#pragma unroll
  for (int off = 32; off > 0; off >>= 1) sq += __shfl_down(sq, off, 64);
  __shared__ float part[4];
  if (lane == 0) part[wv] = sq;
  __syncthreads();
  if (t == 0) atomicAdd(loss, part[0] + part[1] + part[2] + part[3]);
}

__global__ void write_losses(const float* __restrict__ loss, float* __restrict__ out) {
  float m = *loss / (float)(NQ * CD);
  out[OUT_VQ] = m;
  out[OUT_CM] = m;
}

extern "C" void kernel_launch(void* const* d_in, const int* in_sizes, int n_in,
                              void* d_out, int out_size, void* d_ws, size_t ws_size,
                              hipStream_t stream) {
  const float* z = (const float*)d_in[0];
  const float* emb = (const float*)d_in[1];
  float* out = (float*)d_out;
  char* ws = (char*)d_ws;
  unsigned int* qmax = (unsigned int*)(ws + WS_QMAX);
  int* cnt = (int*)(ws + WS_CNT);
  unsigned long long* keys = (unsigned long long*)(ws + WS_KEYS);
  float* loss = (float*)(ws + WS_LOSS);
  int* cand = (int*)(ws + WS_CAND);
  unsigned int* zbf = (unsigned int*)(ws + WS_ZBF);
  unsigned int* ebf = (unsigned int*)(ws + WS_EBF);
  unsigned int* bmax = (unsigned int*)(ws + WS_BMAX);

  convert_kernel<<<1312, 256, 0, stream>>>(z, emb, zbf, ebf, cnt, loss);
  pass1_kernel<<<512, 256, 0, stream>>>(
      (const unsigned short*)zbf, (const unsigned short*)ebf, bmax);
  reduce_qmax_kernel<<<NQ / 8, 256, 0, stream>>>(bmax, qmax);
  collect_kernel<<<512, 256, 0, stream>>>(
      (const unsigned short*)zbf, (const unsigned short*)ebf, qmax, cnt, cand);
  rescore_finalize_kernel<<<NQ / 4, 256, 0, stream>>>(z, emb, cnt, cand, keys, out, loss);
  write_losses<<<1, 1, 0, stream>>>(loss, out);
}